// Round 1
// baseline (351.655 us; speedup 1.0000x reference)
//
#include <hip/hip_runtime.h>
#include <math.h>

#define NG 2048
#define WIMG 128
#define HIMG 128
#define REC 16          // floats per gaussian record
#define TILE 16         // render tile edge

// Record layout (16 floats):
// 0 mux, 1 muy, 2 ic00, 3 ic01, 4 ic11, 5 op,
// 6 pxmin, 7 pxmax, 8 pymin, 9 pymax, 10 c0, 11 c1, 12 c2, 13 depth, 14-15 pad

__global__ void preprocess_kernel(const float* __restrict__ pos,
                                  const float* __restrict__ scales,
                                  const float* __restrict__ rot,
                                  const float* __restrict__ colors,
                                  const float* __restrict__ opac,
                                  const float* __restrict__ view,
                                  float* __restrict__ srec, // N*REC sorted records
                                  int N)
{
    __shared__ float ps[NG * 3];   // 24 KB positions
    __shared__ float zs[NG];       // 8 KB camera-space depths
    const int t = threadIdx.x;
    const int i = blockIdx.x * blockDim.x + t;

    // stage positions
    for (int j = t; j < 3 * N; j += blockDim.x) ps[j] = pos[j];
    __syncthreads();

    // view matrix row 2 (consistent depth for ALL threads)
    const float Rv20 = view[8], Rv21 = view[9], Rv22 = view[10], tv2 = view[11];
    for (int j = t; j < N; j += blockDim.x) {
        zs[j] = Rv20 * ps[3*j] + Rv21 * ps[3*j+1] + Rv22 * ps[3*j+2] + tv2;
    }
    __syncthreads();

    if (i >= N) return;

    // ---- quaternion -> rotation matrix ----
    float qw = rot[4*i+0], qx = rot[4*i+1], qy = rot[4*i+2], qz = rot[4*i+3];
    float nrm = sqrtf(qw*qw + qx*qx + qy*qy + qz*qz) + 1e-8f;
    qw /= nrm; qx /= nrm; qy /= nrm; qz /= nrm;
    float R[3][3];
    R[0][0] = 1.f - 2.f*(qy*qy + qz*qz); R[0][1] = 2.f*(qx*qy + qz*qw); R[0][2] = 2.f*(qx*qz - qy*qw);
    R[1][0] = 2.f*(qx*qy - qz*qw); R[1][1] = 1.f - 2.f*(qx*qx + qz*qz); R[1][2] = 2.f*(qy*qz + qx*qw);
    R[2][0] = 2.f*(qx*qz + qy*qw); R[2][1] = 2.f*(qy*qz - qx*qw); R[2][2] = 1.f - 2.f*(qx*qx + qy*qy);

    float sv[3];
    sv[0] = fmaxf(scales[3*i+0], 1e-6f); sv[0] *= sv[0];
    sv[1] = fmaxf(scales[3*i+1], 1e-6f); sv[1] *= sv[1];
    sv[2] = fmaxf(scales[3*i+2], 1e-6f); sv[2] *= sv[2];

    // cov3d[a][b] = sum_j R[a][j] * sv[j] * R[b][j]
    float C[3][3];
    #pragma unroll
    for (int a = 0; a < 3; ++a)
        #pragma unroll
        for (int b = 0; b < 3; ++b)
            C[a][b] = R[a][0]*sv[0]*R[b][0] + R[a][1]*sv[1]*R[b][1] + R[a][2]*sv[2]*R[b][2];

    // ---- camera transform ----
    float Rv[3][3], tv[3];
    #pragma unroll
    for (int r = 0; r < 3; ++r) {
        Rv[r][0] = view[4*r+0]; Rv[r][1] = view[4*r+1]; Rv[r][2] = view[4*r+2];
        tv[r] = view[4*r+3];
    }
    float Px = ps[3*i], Py = ps[3*i+1], Pz = ps[3*i+2];
    float X = Rv[0][0]*Px + Rv[0][1]*Py + Rv[0][2]*Pz + tv[0];
    float Y = Rv[1][0]*Px + Rv[1][1]*Py + Rv[1][2]*Pz + tv[1];
    float Z = zs[i];   // consistent with rank loop

    float valid = (Z > 0.1f) ? 1.f : 0.f;
    float Zs = fmaxf(Z, 1e-6f);
    const float fx = 110.85125168440814f;  // (W/2)/tan(30deg)
    float mux = fx * X / Zs + 64.f;
    float muy = fx * Y / Zs + 64.f;
    float invZ2 = 1.f / (Zs * Zs);
    float J0[3] = { fx / Zs, 0.f, -fx * X * invZ2 };
    float J1[3] = { 0.f, fx / Zs, -fx * Y * invZ2 };

    // SRt_r[a] = sum_j C[a][j] * Rv[r][j]
    float SRt0[3], SRt1[3];
    #pragma unroll
    for (int a = 0; a < 3; ++a) {
        SRt0[a] = C[a][0]*Rv[0][0] + C[a][1]*Rv[0][1] + C[a][2]*Rv[0][2];
        SRt1[a] = C[a][0]*Rv[1][0] + C[a][1]*Rv[1][1] + C[a][2]*Rv[1][2];
    }
    float c00 = J0[0]*SRt0[0] + J0[1]*SRt0[1] + J0[2]*SRt0[2];
    float c01 = J0[0]*SRt1[0] + J0[1]*SRt1[1] + J0[2]*SRt1[2];
    float c11 = J1[0]*SRt1[0] + J1[1]*SRt1[1] + J1[2]*SRt1[2];

    float trc = c00 + c11;
    float det = c00 * c11 - c01 * c01;
    float disc = fmaxf(trc*trc - 4.f*det, 0.f);
    float lam = 0.5f * (trc + sqrtf(disc));
    float rad = 3.f * sqrtf(fmaxf(lam, 1e-8f));
    c00 += 1e-6f; c11 += 1e-6f;
    float det2 = c00 * c11 - c01 * c01 + 1e-8f;
    float ic00 = c11 / det2, ic01 = -c01 / det2, ic11 = c00 / det2;
    float opv = opac[i] * valid;  // OPACITY_SCALE = 1

    float pxmin = fmaxf(0.f,   truncf(mux - rad));
    float pxmax = fminf(128.f, truncf(mux + rad) + 1.f);
    float pymin = fmaxf(0.f,   truncf(muy - rad));
    float pymax = fminf(128.f, truncf(muy + rad) + 1.f);

    // ---- rank (descending depth, stable) ----
    float di = zs[i];
    int rank = 0;
    for (int j = 0; j < N; ++j) {
        float dj = zs[j];
        rank += (dj > di) || (dj == di && j < i);
    }

    float* o = srec + (size_t)rank * REC;
    o[0] = mux;  o[1] = muy;  o[2] = ic00; o[3] = ic01;
    o[4] = ic11; o[5] = opv;  o[6] = pxmin; o[7] = pxmax;
    o[8] = pymin; o[9] = pymax;
    o[10] = colors[3*i+0]; o[11] = colors[3*i+1]; o[12] = colors[3*i+2];
    o[13] = di; o[14] = 0.f; o[15] = 0.f;
}

__global__ void __launch_bounds__(256)
render_kernel(const float* __restrict__ srec, float* __restrict__ out, int N)
{
    __shared__ float4 gs[256 * 4]; // 16 KB: 256 gaussians x 4 float4
    const int t = threadIdx.x;
    const int tilesX = WIMG / TILE;
    const int tileX = blockIdx.x % tilesX;
    const int tileY = blockIdx.x / tilesX;
    const int lx = t % TILE, ly = t / TILE;
    const int x = tileX * TILE + lx;
    const int y = tileY * TILE + ly;
    const float px = (float)x, py = (float)y;

    float T = 1.f, accR = 0.f, accG = 0.f, accB = 0.f;

    for (int base = 0; base < N; base += 256) {
        __syncthreads();
        int gi = base + t;
        if (gi < N) {
            const float4* src = (const float4*)(srec + (size_t)gi * REC);
            gs[t*4+0] = src[0]; gs[t*4+1] = src[1];
            gs[t*4+2] = src[2]; gs[t*4+3] = src[3];
        }
        __syncthreads();

        int kmax = min(256, N - base);
        if (T >= 1e-6f) {
            for (int k = 0; k < kmax; ++k) {
                float4 a = gs[k*4+0];   // mux, muy, ic00, ic01
                float4 b = gs[k*4+1];   // ic11, op, pxmin, pxmax
                float4 c = gs[k*4+2];   // pymin, pymax, c0, c1
                bool inside = (px >= b.z) && (px < b.w) && (py >= c.x) && (py < c.y);
                if (inside) {
                    float dx = px - a.x, dy = py - a.y;
                    float e = -0.5f * (a.z*dx*dx + 2.f*a.w*dx*dy + b.x*dy*dy);
                    float G = expf(fminf(e, 0.f));
                    float alpha = b.y * G;
                    float w = alpha * T;
                    float4 d = gs[k*4+3]; // c2, depth, pad, pad
                    accR += w * c.z;
                    accG += w * c.w;
                    accB += w * d.x;
                    T *= (1.f - alpha);
                    if (T < 1e-6f) break;
                }
            }
        }
    }

    int idx = (y * WIMG + x) * 3;
    out[idx+0] = accR;
    out[idx+1] = accG;
    out[idx+2] = accB;
}

extern "C" void kernel_launch(void* const* d_in, const int* in_sizes, int n_in,
                              void* d_out, int out_size, void* d_ws, size_t ws_size,
                              hipStream_t stream) {
    const float* pos    = (const float*)d_in[0];
    const float* scales = (const float*)d_in[1];
    const float* rot    = (const float*)d_in[2];
    const float* colors = (const float*)d_in[3];
    const float* opac   = (const float*)d_in[4];
    const float* view   = (const float*)d_in[5];
    float* out = (float*)d_out;
    float* srec = (float*)d_ws;   // N*REC floats = 128 KiB
    const int N = in_sizes[4];    // opacities count

    preprocess_kernel<<<(N + 255) / 256, 256, 0, stream>>>(
        pos, scales, rot, colors, opac, view, srec, N);

    const int nTiles = (WIMG / TILE) * (HIMG / TILE);
    render_kernel<<<nTiles, 256, 0, stream>>>(srec, out, N);
}

// Round 2
// 91.980 us; speedup vs baseline: 3.8232x; 3.8232x over previous
//
#include <hip/hip_runtime.h>
#include <math.h>

#define NG 2048
#define WIMG 128
#define HIMG 128
#define REC 12          // floats per gaussian record (3 x float4)
#define SEG 16          // compositing segments per tile
#define RTILE 8         // render tile edge (8x8 = 64 px)

// Record layout (12 floats = 3 float4):
// r0: mux, muy, ic00, ic01
// r1: ic11, op,  c0,   c1
// r2: c2,  depth, bbox(u8x4 as float bits), pad

__global__ void preprocess_kernel(const float* __restrict__ pos,
                                  const float* __restrict__ scales,
                                  const float* __restrict__ rot,
                                  const float* __restrict__ colors,
                                  const float* __restrict__ opac,
                                  const float* __restrict__ view,
                                  float* __restrict__ srec, // N*REC sorted records
                                  int N)
{
    __shared__ float ps[NG * 3];   // 24 KB positions
    __shared__ float zs[NG];       // 8 KB camera-space depths
    const int t = threadIdx.x;
    const int i = blockIdx.x * blockDim.x + t;

    // stage positions
    for (int j = t; j < 3 * N; j += blockDim.x) ps[j] = pos[j];
    __syncthreads();

    // view matrix row 2 (single shared code path -> bitwise-consistent depths)
    const float Rv20 = view[8], Rv21 = view[9], Rv22 = view[10], tv2 = view[11];
    for (int j = t; j < N; j += blockDim.x) {
        zs[j] = Rv20 * ps[3*j] + Rv21 * ps[3*j+1] + Rv22 * ps[3*j+2] + tv2;
    }
    __syncthreads();

    if (i >= N) return;

    // ---- quaternion -> rotation matrix ----
    float qw = rot[4*i+0], qx = rot[4*i+1], qy = rot[4*i+2], qz = rot[4*i+3];
    float nrm = sqrtf(qw*qw + qx*qx + qy*qy + qz*qz) + 1e-8f;
    qw /= nrm; qx /= nrm; qy /= nrm; qz /= nrm;
    float R[3][3];
    R[0][0] = 1.f - 2.f*(qy*qy + qz*qz); R[0][1] = 2.f*(qx*qy + qz*qw); R[0][2] = 2.f*(qx*qz - qy*qw);
    R[1][0] = 2.f*(qx*qy - qz*qw); R[1][1] = 1.f - 2.f*(qx*qx + qz*qz); R[1][2] = 2.f*(qy*qz + qx*qw);
    R[2][0] = 2.f*(qx*qz + qy*qw); R[2][1] = 2.f*(qy*qz - qx*qw); R[2][2] = 1.f - 2.f*(qx*qx + qy*qy);

    float sv[3];
    sv[0] = fmaxf(scales[3*i+0], 1e-6f); sv[0] *= sv[0];
    sv[1] = fmaxf(scales[3*i+1], 1e-6f); sv[1] *= sv[1];
    sv[2] = fmaxf(scales[3*i+2], 1e-6f); sv[2] *= sv[2];

    float C[3][3];
    #pragma unroll
    for (int a = 0; a < 3; ++a)
        #pragma unroll
        for (int b = 0; b < 3; ++b)
            C[a][b] = R[a][0]*sv[0]*R[b][0] + R[a][1]*sv[1]*R[b][1] + R[a][2]*sv[2]*R[b][2];

    float Rv[3][3], tv[3];
    #pragma unroll
    for (int r = 0; r < 3; ++r) {
        Rv[r][0] = view[4*r+0]; Rv[r][1] = view[4*r+1]; Rv[r][2] = view[4*r+2];
        tv[r] = view[4*r+3];
    }
    float Px = ps[3*i], Py = ps[3*i+1], Pz = ps[3*i+2];
    float X = Rv[0][0]*Px + Rv[0][1]*Py + Rv[0][2]*Pz + tv[0];
    float Y = Rv[1][0]*Px + Rv[1][1]*Py + Rv[1][2]*Pz + tv[1];
    float Z = zs[i];

    float valid = (Z > 0.1f) ? 1.f : 0.f;
    float Zs = fmaxf(Z, 1e-6f);
    const float fx = 110.85125168440814f;  // (W/2)/tan(30deg)
    float mux = fx * X / Zs + 64.f;
    float muy = fx * Y / Zs + 64.f;
    float invZ2 = 1.f / (Zs * Zs);
    float J0[3] = { fx / Zs, 0.f, -fx * X * invZ2 };
    float J1[3] = { 0.f, fx / Zs, -fx * Y * invZ2 };

    float SRt0[3], SRt1[3];
    #pragma unroll
    for (int a = 0; a < 3; ++a) {
        SRt0[a] = C[a][0]*Rv[0][0] + C[a][1]*Rv[0][1] + C[a][2]*Rv[0][2];
        SRt1[a] = C[a][0]*Rv[1][0] + C[a][1]*Rv[1][1] + C[a][2]*Rv[1][2];
    }
    float c00 = J0[0]*SRt0[0] + J0[1]*SRt0[1] + J0[2]*SRt0[2];
    float c01 = J0[0]*SRt1[0] + J0[1]*SRt1[1] + J0[2]*SRt1[2];
    float c11 = J1[0]*SRt1[0] + J1[1]*SRt1[1] + J1[2]*SRt1[2];

    float trc = c00 + c11;
    float det = c00 * c11 - c01 * c01;
    float disc = fmaxf(trc*trc - 4.f*det, 0.f);
    float lam = 0.5f * (trc + sqrtf(disc));
    float rad = 3.f * sqrtf(fmaxf(lam, 1e-8f));
    c00 += 1e-6f; c11 += 1e-6f;
    float det2 = c00 * c11 - c01 * c01 + 1e-8f;
    float ic00 = c11 / det2, ic01 = -c01 / det2, ic11 = c00 / det2;
    float opv = opac[i] * valid;

    float pxmin = fmaxf(0.f,   truncf(mux - rad));
    float pxmax = fminf(128.f, truncf(mux + rad) + 1.f);
    float pymin = fmaxf(0.f,   truncf(muy - rad));
    float pymax = fminf(128.f, truncf(muy + rad) + 1.f);

    // pack bbox as u8x4 (clamped so out-of-range => always-false test)
    int ixmin = (int)fminf(pxmin, 255.f);
    int ixmax = (int)fmaxf(pxmax, 0.f);     // already <=128
    int iymin = (int)fminf(pymin, 255.f);
    int iymax = (int)fmaxf(pymax, 0.f);
    unsigned int bbox = (unsigned)ixmin | ((unsigned)ixmax << 8)
                      | ((unsigned)iymin << 16) | ((unsigned)iymax << 24);

    // ---- rank (descending depth, stable) ----
    float di = zs[i];
    int rank = 0;
    for (int j = 0; j < N; ++j) {
        float dj = zs[j];
        rank += (dj > di) || (dj == di && j < i);
    }

    float* o = srec + (size_t)rank * REC;
    o[0]  = mux;  o[1]  = muy;  o[2] = ic00; o[3] = ic01;
    o[4]  = ic11; o[5]  = opv;  o[6] = colors[3*i+0]; o[7] = colors[3*i+1];
    o[8]  = colors[3*i+2]; o[9] = di;
    o[10] = __uint_as_float(bbox); o[11] = 0.f;
}

__global__ void __launch_bounds__(1024)
render_kernel(const float* __restrict__ srec, float* __restrict__ out, int N)
{
    __shared__ float4 part[SEG][64];   // 16 KB partial (R,G,B,T) per segment x pixel
    const int t   = threadIdx.x;
    const int px  = t & 63;            // pixel within 8x8 tile
    const int seg = t >> 6;            // segment id = wave id
    const int tilesX = WIMG / RTILE;
    const int tileX = blockIdx.x % tilesX;
    const int tileY = blockIdx.x / tilesX;
    const int lx = px & (RTILE - 1), ly = px / RTILE;
    const int x = tileX * RTILE + lx;
    const int y = tileY * RTILE + ly;
    const float fpx = (float)x, fpy = (float)y;

    const int chunk = (N + SEG - 1) / SEG;
    const int k0 = seg * chunk;
    const int k1 = min(k0 + chunk, N);

    float T = 1.f, aR = 0.f, aG = 0.f, aB = 0.f;
    const float4* rec = (const float4*)srec;

    for (int k = k0; k < k1; ++k) {
        float4 a = rec[k*3+0];   // mux, muy, ic00, ic01
        float4 b = rec[k*3+1];   // ic11, op, c0, c1
        float4 c = rec[k*3+2];   // c2, depth, bbox, pad
        unsigned int bbox = __float_as_uint(c.z);
        int xmin = bbox & 255, xmax = (bbox >> 8) & 255;
        int ymin = (bbox >> 16) & 255, ymax = bbox >> 24;
        if (x >= xmin && x < xmax && y >= ymin && y < ymax) {
            float dx = fpx - a.x, dy = fpy - a.y;
            float e = -0.5f * (a.z*dx*dx + 2.f*a.w*dx*dy + b.x*dy*dy);
            float G = __expf(fminf(e, 0.f));
            float alpha = b.y * G;
            float w = alpha * T;
            aR += w * b.z;
            aG += w * b.w;
            aB += w * c.x;
            T *= (1.f - alpha);
        }
    }

    part[seg][px] = make_float4(aR, aG, aB, T);
    __syncthreads();

    if (t < 64) {
        float accR = 0.f, accG = 0.f, accB = 0.f, Tacc = 1.f;
        #pragma unroll
        for (int s = 0; s < SEG; ++s) {
            float4 p = part[s][px];
            accR += Tacc * p.x;
            accG += Tacc * p.y;
            accB += Tacc * p.z;
            Tacc *= p.w;
        }
        int idx = (y * WIMG + x) * 3;
        out[idx+0] = accR;
        out[idx+1] = accG;
        out[idx+2] = accB;
    }
}

extern "C" void kernel_launch(void* const* d_in, const int* in_sizes, int n_in,
                              void* d_out, int out_size, void* d_ws, size_t ws_size,
                              hipStream_t stream) {
    const float* pos    = (const float*)d_in[0];
    const float* scales = (const float*)d_in[1];
    const float* rot    = (const float*)d_in[2];
    const float* colors = (const float*)d_in[3];
    const float* opac   = (const float*)d_in[4];
    const float* view   = (const float*)d_in[5];
    float* out = (float*)d_out;
    float* srec = (float*)d_ws;   // N*REC floats = 96 KiB
    const int N = in_sizes[4];    // opacities count

    preprocess_kernel<<<(N + 255) / 256, 256, 0, stream>>>(
        pos, scales, rot, colors, opac, view, srec, N);

    const int nTiles = (WIMG / RTILE) * (HIMG / RTILE);
    render_kernel<<<nTiles, 1024, 0, stream>>>(srec, out, N);
}

// Round 3
// 43.284 us; speedup vs baseline: 8.1244x; 2.1250x over previous
//
#include <hip/hip_runtime.h>
#include <math.h>

#define NG 2048
#define WIMG 128
#define HIMG 128
#define REC 12          // floats per gaussian record (3 x float4)
#define SEG 16          // compositing segments per tile
#define RTILE 8         // render tile edge (8x8 = 64 px)
#define GPB 4           // gaussians per preprocess block (1 wave each)

// Record layout (12 floats = 3 float4):
// r0: mux, muy, ic00, ic01
// r1: ic11, op,  c0,   c1
// r2: c2,  depth, bbox(u8x4 as float bits), pad

__global__ void __launch_bounds__(256)
preprocess_kernel(const float* __restrict__ pos,
                  const float* __restrict__ scales,
                  const float* __restrict__ rot,
                  const float* __restrict__ colors,
                  const float* __restrict__ opac,
                  const float* __restrict__ view,
                  float* __restrict__ srec, // N*REC sorted records
                  int N)
{
    __shared__ float ps[NG * 3];   // 24 KB positions
    __shared__ float zs[NG];       // 8 KB camera-space depths
    const int t = threadIdx.x;

    // stage positions (same in every block)
    for (int j = t; j < 3 * N; j += 256) ps[j] = pos[j];
    __syncthreads();

    // depths — identical expression in every block => bitwise-consistent
    const float Rv20 = view[8], Rv21 = view[9], Rv22 = view[10], tv2 = view[11];
    for (int j = t; j < N; j += 256) {
        zs[j] = Rv20 * ps[3*j] + Rv21 * ps[3*j+1] + Rv22 * ps[3*j+2] + tv2;
    }
    __syncthreads();

    const int wid = t >> 6, lane = t & 63;
    const int i = blockIdx.x * GPB + wid;
    if (i >= N) return;

    // ---- rank (descending depth, stable), split across 64 lanes ----
    const float di = zs[i];
    int cnt = 0;
    for (int j = lane; j < N; j += 64) {
        float dj = zs[j];
        cnt += (dj > di) || (dj == di && j < i);
    }
    #pragma unroll
    for (int off = 32; off; off >>= 1) cnt += __shfl_xor(cnt, off);
    const int rank = cnt;   // all lanes agree

    // ---- per-gaussian math (redundant on all lanes; no divergence) ----
    float qw = rot[4*i+0], qx = rot[4*i+1], qy = rot[4*i+2], qz = rot[4*i+3];
    float nrm = sqrtf(qw*qw + qx*qx + qy*qy + qz*qz) + 1e-8f;
    qw /= nrm; qx /= nrm; qy /= nrm; qz /= nrm;
    float R[3][3];
    R[0][0] = 1.f - 2.f*(qy*qy + qz*qz); R[0][1] = 2.f*(qx*qy + qz*qw); R[0][2] = 2.f*(qx*qz - qy*qw);
    R[1][0] = 2.f*(qx*qy - qz*qw); R[1][1] = 1.f - 2.f*(qx*qx + qz*qz); R[1][2] = 2.f*(qy*qz + qx*qw);
    R[2][0] = 2.f*(qx*qz + qy*qw); R[2][1] = 2.f*(qy*qz - qx*qw); R[2][2] = 1.f - 2.f*(qx*qx + qy*qy);

    float sv[3];
    sv[0] = fmaxf(scales[3*i+0], 1e-6f); sv[0] *= sv[0];
    sv[1] = fmaxf(scales[3*i+1], 1e-6f); sv[1] *= sv[1];
    sv[2] = fmaxf(scales[3*i+2], 1e-6f); sv[2] *= sv[2];

    float C[3][3];
    #pragma unroll
    for (int a = 0; a < 3; ++a)
        #pragma unroll
        for (int b = 0; b < 3; ++b)
            C[a][b] = R[a][0]*sv[0]*R[b][0] + R[a][1]*sv[1]*R[b][1] + R[a][2]*sv[2]*R[b][2];

    float Rv[3][3], tv[3];
    #pragma unroll
    for (int r = 0; r < 3; ++r) {
        Rv[r][0] = view[4*r+0]; Rv[r][1] = view[4*r+1]; Rv[r][2] = view[4*r+2];
        tv[r] = view[4*r+3];
    }
    float Px = ps[3*i], Py = ps[3*i+1], Pz = ps[3*i+2];
    float X = Rv[0][0]*Px + Rv[0][1]*Py + Rv[0][2]*Pz + tv[0];
    float Y = Rv[1][0]*Px + Rv[1][1]*Py + Rv[1][2]*Pz + tv[1];
    float Z = di;

    float valid = (Z > 0.1f) ? 1.f : 0.f;
    float Zs = fmaxf(Z, 1e-6f);
    const float fx = 110.85125168440814f;  // (W/2)/tan(30deg)
    float mux = fx * X / Zs + 64.f;
    float muy = fx * Y / Zs + 64.f;
    float invZ2 = 1.f / (Zs * Zs);
    float J0[3] = { fx / Zs, 0.f, -fx * X * invZ2 };
    float J1[3] = { 0.f, fx / Zs, -fx * Y * invZ2 };

    float SRt0[3], SRt1[3];
    #pragma unroll
    for (int a = 0; a < 3; ++a) {
        SRt0[a] = C[a][0]*Rv[0][0] + C[a][1]*Rv[0][1] + C[a][2]*Rv[0][2];
        SRt1[a] = C[a][0]*Rv[1][0] + C[a][1]*Rv[1][1] + C[a][2]*Rv[1][2];
    }
    float c00 = J0[0]*SRt0[0] + J0[1]*SRt0[1] + J0[2]*SRt0[2];
    float c01 = J0[0]*SRt1[0] + J0[1]*SRt1[1] + J0[2]*SRt1[2];
    float c11 = J1[0]*SRt1[0] + J1[1]*SRt1[1] + J1[2]*SRt1[2];

    float trc = c00 + c11;
    float det = c00 * c11 - c01 * c01;
    float disc = fmaxf(trc*trc - 4.f*det, 0.f);
    float lam = 0.5f * (trc + sqrtf(disc));
    float rad = 3.f * sqrtf(fmaxf(lam, 1e-8f));
    c00 += 1e-6f; c11 += 1e-6f;
    float det2 = c00 * c11 - c01 * c01 + 1e-8f;
    float ic00 = c11 / det2, ic01 = -c01 / det2, ic11 = c00 / det2;
    float opv = opac[i] * valid;

    float pxmin = fmaxf(0.f,   truncf(mux - rad));
    float pxmax = fminf(128.f, truncf(mux + rad) + 1.f);
    float pymin = fmaxf(0.f,   truncf(muy - rad));
    float pymax = fminf(128.f, truncf(muy + rad) + 1.f);

    int ixmin = (int)fminf(pxmin, 255.f);
    int ixmax = (int)fmaxf(pxmax, 0.f);
    int iymin = (int)fminf(pymin, 255.f);
    int iymax = (int)fmaxf(pymax, 0.f);
    unsigned int bbox = (unsigned)ixmin | ((unsigned)ixmax << 8)
                      | ((unsigned)iymin << 16) | ((unsigned)iymax << 24);

    if (lane == 0) {
        float4* o = (float4*)(srec + (size_t)rank * REC);
        o[0] = make_float4(mux, muy, ic00, ic01);
        o[1] = make_float4(ic11, opv, colors[3*i+0], colors[3*i+1]);
        o[2] = make_float4(colors[3*i+2], di, __uint_as_float(bbox), 0.f);
    }
}

__global__ void __launch_bounds__(1024)
render_kernel(const float* __restrict__ srec, float* __restrict__ out, int N)
{
    __shared__ float4 part[SEG][64];   // 16 KB partial (R,G,B,T) per segment x pixel
    const int t   = threadIdx.x;
    const int px  = t & 63;            // pixel within 8x8 tile
    const int seg = t >> 6;            // segment id = wave id
    const int tilesX = WIMG / RTILE;
    const int tileX = blockIdx.x % tilesX;
    const int tileY = blockIdx.x / tilesX;
    const int lx = px & (RTILE - 1), ly = px / RTILE;
    const int x = tileX * RTILE + lx;
    const int y = tileY * RTILE + ly;
    const float fpx = (float)x, fpy = (float)y;

    const int chunk = (N + SEG - 1) / SEG;
    const int k0 = seg * chunk;
    const int k1 = min(k0 + chunk, N);

    float T = 1.f, aR = 0.f, aG = 0.f, aB = 0.f;
    const float4* rec = (const float4*)srec;

    for (int k = k0; k < k1; ++k) {
        float4 a = rec[k*3+0];   // mux, muy, ic00, ic01
        float4 b = rec[k*3+1];   // ic11, op, c0, c1
        float4 c = rec[k*3+2];   // c2, depth, bbox, pad
        unsigned int bbox = __float_as_uint(c.z);
        int xmin = bbox & 255, xmax = (bbox >> 8) & 255;
        int ymin = (bbox >> 16) & 255, ymax = bbox >> 24;
        if (x >= xmin && x < xmax && y >= ymin && y < ymax) {
            float dx = fpx - a.x, dy = fpy - a.y;
            float e = -0.5f * (a.z*dx*dx + 2.f*a.w*dx*dy + b.x*dy*dy);
            float G = __expf(fminf(e, 0.f));
            float alpha = b.y * G;
            float w = alpha * T;
            aR += w * b.z;
            aG += w * b.w;
            aB += w * c.x;
            T *= (1.f - alpha);
        }
    }

    part[seg][px] = make_float4(aR, aG, aB, T);
    __syncthreads();

    if (t < 64) {
        float accR = 0.f, accG = 0.f, accB = 0.f, Tacc = 1.f;
        #pragma unroll
        for (int s = 0; s < SEG; ++s) {
            float4 p = part[s][px];
            accR += Tacc * p.x;
            accG += Tacc * p.y;
            accB += Tacc * p.z;
            Tacc *= p.w;
        }
        int idx = (y * WIMG + x) * 3;
        out[idx+0] = accR;
        out[idx+1] = accG;
        out[idx+2] = accB;
    }
}

extern "C" void kernel_launch(void* const* d_in, const int* in_sizes, int n_in,
                              void* d_out, int out_size, void* d_ws, size_t ws_size,
                              hipStream_t stream) {
    const float* pos    = (const float*)d_in[0];
    const float* scales = (const float*)d_in[1];
    const float* rot    = (const float*)d_in[2];
    const float* colors = (const float*)d_in[3];
    const float* opac   = (const float*)d_in[4];
    const float* view   = (const float*)d_in[5];
    float* out = (float*)d_out;
    float* srec = (float*)d_ws;   // N*REC floats = 96 KiB
    const int N = in_sizes[4];    // opacities count

    const int nPreBlocks = (N + GPB - 1) / GPB;
    preprocess_kernel<<<nPreBlocks, 256, 0, stream>>>(
        pos, scales, rot, colors, opac, view, srec, N);

    const int nTiles = (WIMG / RTILE) * (HIMG / RTILE);
    render_kernel<<<nTiles, 1024, 0, stream>>>(srec, out, N);
}

// Round 4
// 16.349 us; speedup vs baseline: 21.5091x; 2.6475x over previous
//
#include <hip/hip_runtime.h>
#include <math.h>

#define NG 2048
#define WIMG 128
#define HIMG 128
#define REC 12          // floats per gaussian record (3 x float4)
#define SEG 16          // compositing segments per tile (= waves per block)
#define RTILE 8         // render tile edge (8x8 = 64 px = 1 wave)
#define GPB 4           // gaussians per preprocess block (1 wave each)

// Record layout (12 floats = 3 float4):
// r0: mux, muy, ic00, ic01
// r1: ic11, op,  c0,   c1
// r2: c2,  depth, bbox(u8x4 as float bits), pad

__global__ void __launch_bounds__(256)
preprocess_kernel(const float* __restrict__ pos,
                  const float* __restrict__ scales,
                  const float* __restrict__ rot,
                  const float* __restrict__ colors,
                  const float* __restrict__ opac,
                  const float* __restrict__ view,
                  float* __restrict__ srec, // N*REC sorted records
                  int N)
{
    __shared__ float ps[NG * 3];   // 24 KB positions
    __shared__ float zs[NG];       // 8 KB camera-space depths
    const int t = threadIdx.x;

    // stage positions (same in every block)
    for (int j = t; j < 3 * N; j += 256) ps[j] = pos[j];
    __syncthreads();

    // depths — identical expression in every block => bitwise-consistent
    const float Rv20 = view[8], Rv21 = view[9], Rv22 = view[10], tv2 = view[11];
    for (int j = t; j < N; j += 256) {
        zs[j] = Rv20 * ps[3*j] + Rv21 * ps[3*j+1] + Rv22 * ps[3*j+2] + tv2;
    }
    __syncthreads();

    const int wid = t >> 6, lane = t & 63;
    const int i = blockIdx.x * GPB + wid;
    if (i >= N) return;

    // ---- rank (descending depth, stable), split across 64 lanes ----
    const float di = zs[i];
    int cnt = 0;
    for (int j = lane; j < N; j += 64) {
        float dj = zs[j];
        cnt += (dj > di) || (dj == di && j < i);
    }
    #pragma unroll
    for (int off = 32; off; off >>= 1) cnt += __shfl_xor(cnt, off);
    const int rank = cnt;   // all lanes agree

    // ---- per-gaussian math (redundant on all lanes; no divergence) ----
    float qw = rot[4*i+0], qx = rot[4*i+1], qy = rot[4*i+2], qz = rot[4*i+3];
    float nrm = sqrtf(qw*qw + qx*qx + qy*qy + qz*qz) + 1e-8f;
    qw /= nrm; qx /= nrm; qy /= nrm; qz /= nrm;
    float R[3][3];
    R[0][0] = 1.f - 2.f*(qy*qy + qz*qz); R[0][1] = 2.f*(qx*qy + qz*qw); R[0][2] = 2.f*(qx*qz - qy*qw);
    R[1][0] = 2.f*(qx*qy - qz*qw); R[1][1] = 1.f - 2.f*(qx*qx + qz*qz); R[1][2] = 2.f*(qy*qz + qx*qw);
    R[2][0] = 2.f*(qx*qz + qy*qw); R[2][1] = 2.f*(qy*qz - qx*qw); R[2][2] = 1.f - 2.f*(qx*qx + qy*qy);

    float sv[3];
    sv[0] = fmaxf(scales[3*i+0], 1e-6f); sv[0] *= sv[0];
    sv[1] = fmaxf(scales[3*i+1], 1e-6f); sv[1] *= sv[1];
    sv[2] = fmaxf(scales[3*i+2], 1e-6f); sv[2] *= sv[2];

    float C[3][3];
    #pragma unroll
    for (int a = 0; a < 3; ++a)
        #pragma unroll
        for (int b = 0; b < 3; ++b)
            C[a][b] = R[a][0]*sv[0]*R[b][0] + R[a][1]*sv[1]*R[b][1] + R[a][2]*sv[2]*R[b][2];

    float Rv[3][3], tv[3];
    #pragma unroll
    for (int r = 0; r < 3; ++r) {
        Rv[r][0] = view[4*r+0]; Rv[r][1] = view[4*r+1]; Rv[r][2] = view[4*r+2];
        tv[r] = view[4*r+3];
    }
    float Px = ps[3*i], Py = ps[3*i+1], Pz = ps[3*i+2];
    float X = Rv[0][0]*Px + Rv[0][1]*Py + Rv[0][2]*Pz + tv[0];
    float Y = Rv[1][0]*Px + Rv[1][1]*Py + Rv[1][2]*Pz + tv[1];
    float Z = di;

    float valid = (Z > 0.1f) ? 1.f : 0.f;
    float Zs = fmaxf(Z, 1e-6f);
    const float fx = 110.85125168440814f;  // (W/2)/tan(30deg)
    float mux = fx * X / Zs + 64.f;
    float muy = fx * Y / Zs + 64.f;
    float invZ2 = 1.f / (Zs * Zs);
    float J0[3] = { fx / Zs, 0.f, -fx * X * invZ2 };
    float J1[3] = { 0.f, fx / Zs, -fx * Y * invZ2 };

    float SRt0[3], SRt1[3];
    #pragma unroll
    for (int a = 0; a < 3; ++a) {
        SRt0[a] = C[a][0]*Rv[0][0] + C[a][1]*Rv[0][1] + C[a][2]*Rv[0][2];
        SRt1[a] = C[a][0]*Rv[1][0] + C[a][1]*Rv[1][1] + C[a][2]*Rv[1][2];
    }
    float c00 = J0[0]*SRt0[0] + J0[1]*SRt0[1] + J0[2]*SRt0[2];
    float c01 = J0[0]*SRt1[0] + J0[1]*SRt1[1] + J0[2]*SRt1[2];
    float c11 = J1[0]*SRt1[0] + J1[1]*SRt1[1] + J1[2]*SRt1[2];

    float trc = c00 + c11;
    float det = c00 * c11 - c01 * c01;
    float disc = fmaxf(trc*trc - 4.f*det, 0.f);
    float lam = 0.5f * (trc + sqrtf(disc));
    float rad = 3.f * sqrtf(fmaxf(lam, 1e-8f));
    c00 += 1e-6f; c11 += 1e-6f;
    float det2 = c00 * c11 - c01 * c01 + 1e-8f;
    float ic00 = c11 / det2, ic01 = -c01 / det2, ic11 = c00 / det2;
    float opv = opac[i] * valid;

    float pxmin = fmaxf(0.f,   truncf(mux - rad));
    float pxmax = fminf(128.f, truncf(mux + rad) + 1.f);
    float pymin = fmaxf(0.f,   truncf(muy - rad));
    float pymax = fminf(128.f, truncf(muy + rad) + 1.f);

    int ixmin = (int)fminf(pxmin, 255.f);
    int ixmax = (int)fmaxf(pxmax, 0.f);
    int iymin = (int)fminf(pymin, 255.f);
    int iymax = (int)fmaxf(pymax, 0.f);
    unsigned int bbox = (unsigned)ixmin | ((unsigned)ixmax << 8)
                      | ((unsigned)iymin << 16) | ((unsigned)iymax << 24);

    if (lane == 0) {
        float4* o = (float4*)(srec + (size_t)rank * REC);
        o[0] = make_float4(mux, muy, ic00, ic01);
        o[1] = make_float4(ic11, opv, colors[3*i+0], colors[3*i+1]);
        o[2] = make_float4(colors[3*i+2], di, __uint_as_float(bbox), 0.f);
    }
}

__global__ void __launch_bounds__(1024)
render_kernel(const float* __restrict__ srec, float* __restrict__ out, int N)
{
    __shared__ float4 part[SEG][64];   // 16 KB partial (R,G,B,T) per segment x pixel
    const int t    = threadIdx.x;
    const int lane = t & 63;           // pixel within 8x8 tile AND gaussian-lane
    const int seg  = t >> 6;           // segment id = wave id
    const int tilesX = WIMG / RTILE;
    const int tileX = blockIdx.x % tilesX;
    const int tileY = blockIdx.x / tilesX;
    const int x = tileX * RTILE + (lane & (RTILE - 1));
    const int y = tileY * RTILE + (lane / RTILE);
    const float fpx = (float)x, fpy = (float)y;
    // tile rect for wave-level cull
    const int tx0 = tileX * RTILE, tx1 = tx0 + RTILE;
    const int ty0 = tileY * RTILE, ty1 = ty0 + RTILE;

    const int chunk = (N + SEG - 1) / SEG;   // 128 for N=2048
    const int k0 = seg * chunk;
    const int k1 = min(k0 + chunk, N);

    float T = 1.f, aR = 0.f, aG = 0.f, aB = 0.f;
    const float4* rec = (const float4*)srec;

    for (int base = k0; base < k1; base += 64) {
        const int g = base + lane;        // lane acts as gaussian index
        float4 r0 = make_float4(0,0,0,0), r1 = r0, r2 = r0;
        bool hit = false;
        if (g < k1) {
            r0 = rec[g*3+0];              // mux, muy, ic00, ic01
            r1 = rec[g*3+1];              // ic11, op, c0, c1
            r2 = rec[g*3+2];              // c2, depth, bbox, pad
            unsigned bb = __float_as_uint(r2.z);
            int xmin = bb & 255, xmax = (bb >> 8) & 255;
            int ymin = (bb >> 16) & 255, ymax = bb >> 24;
            hit = (xmin < tx1) && (xmax > tx0) && (ymin < ty1) && (ymax > ty0);
        }
        unsigned long long m = __ballot(hit);
        while (m) {
            const int b = __ffsll((long long)m) - 1;   // ascending = depth order
            m &= m - 1;
            // broadcast record from lane b; lane acts as pixel now
            float mux = __shfl(r0.x, b), muy = __shfl(r0.y, b);
            float i00 = __shfl(r0.z, b), i01 = __shfl(r0.w, b);
            float i11 = __shfl(r1.x, b), op  = __shfl(r1.y, b);
            float c0  = __shfl(r1.z, b), c1  = __shfl(r1.w, b);
            float c2  = __shfl(r2.x, b);
            unsigned bb = __float_as_uint(__shfl(r2.z, b));
            int xmin = bb & 255, xmax = (bb >> 8) & 255;
            int ymin = (bb >> 16) & 255, ymax = bb >> 24;
            bool inside = (x >= xmin) && (x < xmax) && (y >= ymin) && (y < ymax);
            float dx = fpx - mux, dy = fpy - muy;
            float e = -0.5f * (i00*dx*dx + 2.f*i01*dx*dy + i11*dy*dy);
            float G = __expf(fminf(e, 0.f));
            float alpha = inside ? (op * G) : 0.f;
            float w = alpha * T;
            aR += w * c0;
            aG += w * c1;
            aB += w * c2;
            T *= (1.f - alpha);
        }
    }

    part[seg][lane] = make_float4(aR, aG, aB, T);
    __syncthreads();

    if (t < 64) {
        float accR = 0.f, accG = 0.f, accB = 0.f, Tacc = 1.f;
        #pragma unroll
        for (int s = 0; s < SEG; ++s) {
            float4 p = part[s][t];
            accR += Tacc * p.x;
            accG += Tacc * p.y;
            accB += Tacc * p.z;
            Tacc *= p.w;
        }
        int idx = (y * WIMG + x) * 3;
        out[idx+0] = accR;
        out[idx+1] = accG;
        out[idx+2] = accB;
    }
}

extern "C" void kernel_launch(void* const* d_in, const int* in_sizes, int n_in,
                              void* d_out, int out_size, void* d_ws, size_t ws_size,
                              hipStream_t stream) {
    const float* pos    = (const float*)d_in[0];
    const float* scales = (const float*)d_in[1];
    const float* rot    = (const float*)d_in[2];
    const float* colors = (const float*)d_in[3];
    const float* opac   = (const float*)d_in[4];
    const float* view   = (const float*)d_in[5];
    float* out = (float*)d_out;
    float* srec = (float*)d_ws;   // N*REC floats = 96 KiB
    const int N = in_sizes[4];    // opacities count

    const int nPreBlocks = (N + GPB - 1) / GPB;
    preprocess_kernel<<<nPreBlocks, 256, 0, stream>>>(
        pos, scales, rot, colors, opac, view, srec, N);

    const int nTiles = (WIMG / RTILE) * (HIMG / RTILE);
    render_kernel<<<nTiles, 1024, 0, stream>>>(srec, out, N);
}